// Round 6
// baseline (1483.635 us; speedup 1.0000x reference)
//
#include <hip/hip_runtime.h>
#include <hip/hip_bf16.h>
#include <hip/hip_cooperative_groups.h>

namespace cg = cooperative_groups;

#define N_NODES 50000
#define N_EDGES 800000
#define TOT_EDGES (N_EDGES + N_NODES)
#define IN_DIM 256
#define OUT_DIM 256   // HEADS * HID
#define HEADS 4
#define NEG_SLOPE 0.2f
#define MAXD 128       // LDS alpha-cache per node
#define GRID 1024      // target 4 blocks/CU x 256 CU
#define NCHUNK 1024    // scan chunks (mega)
#define CHN 49         // nodes per scan chunk (1024*49 >= 50000)
#define GEMM_JOBS 3125 // 16 rows each = 50000
#define EXT_JOBS 375   // extract/hist chunks
#define TOTAL_JOBS (GEMM_JOBS + EXT_JOBS)
#define AGG_JOBS 12500 // 4 nodes each

typedef __bf16 bf16x8 __attribute__((ext_vector_type(8)));
typedef float f32x4 __attribute__((ext_vector_type(4)));

__device__ __forceinline__ float b2f(unsigned short u) {
    union { float f; unsigned int i; } v; v.i = ((unsigned int)u) << 16; return v.f;
}

// ---------------- shared device functions (used by mega AND fallback) -------

// block-uniform int64-vs-int32 detection (all threads must call)
__device__ __forceinline__ bool detect64(const int* __restrict__ ei, int t) {
    int nz = 0;
    for (int i = t; i < 1024; i += 256)
        if (ei[2 * i + 1] != 0) nz++;
    return __syncthreads_count(nz) == 0;
}

// 16-row GEMM tile j: h[j*16 .. j*16+16) = x@W, + fused attention logits
__device__ __forceinline__ void do_gemm16(
        int j, const float* __restrict__ x, const __bf16* __restrict__ Wt,
        const float* __restrict__ att_s, const float* __restrict__ att_d,
        __bf16* __restrict__ h, float* __restrict__ a_src, float* __restrict__ a_dst,
        int wave, int lane) {
    const int cc   = lane & 15;
    const int quad = lane >> 4;
    const int mbase = j * 16;
    const int n0    = wave * 64;
    f32x4 acc0 = {0.f, 0.f, 0.f, 0.f};
    f32x4 acc1 = acc0, acc2 = acc0, acc3 = acc0;
    const float4* x4 = (const float4*)x;
    const int arow = mbase + cc;
    for (int k0 = 0; k0 < IN_DIM; k0 += 32) {
        bf16x8 b0 = *(const bf16x8*)(Wt + (size_t)(n0 + cc)      * IN_DIM + k0 + quad * 8);
        bf16x8 b1 = *(const bf16x8*)(Wt + (size_t)(n0 + 16 + cc) * IN_DIM + k0 + quad * 8);
        bf16x8 b2 = *(const bf16x8*)(Wt + (size_t)(n0 + 32 + cc) * IN_DIM + k0 + quad * 8);
        bf16x8 b3 = *(const bf16x8*)(Wt + (size_t)(n0 + 48 + cc) * IN_DIM + k0 + quad * 8);
        float4 lo = x4[(size_t)arow * 64 + (k0 >> 2) + quad * 2];
        float4 hi = x4[(size_t)arow * 64 + (k0 >> 2) + quad * 2 + 1];
        bf16x8 a;
        a[0] = (__bf16)lo.x; a[1] = (__bf16)lo.y; a[2] = (__bf16)lo.z; a[3] = (__bf16)lo.w;
        a[4] = (__bf16)hi.x; a[5] = (__bf16)hi.y; a[6] = (__bf16)hi.z; a[7] = (__bf16)hi.w;
        acc0 = __builtin_amdgcn_mfma_f32_16x16x32_bf16(a, b0, acc0, 0, 0, 0);
        acc1 = __builtin_amdgcn_mfma_f32_16x16x32_bf16(a, b1, acc1, 0, 0, 0);
        acc2 = __builtin_amdgcn_mfma_f32_16x16x32_bf16(a, b2, acc2, 0, 0, 0);
        acc3 = __builtin_amdgcn_mfma_f32_16x16x32_bf16(a, b3, acc3, 0, 0, 0);
    }
    float as0 = att_s[n0 + cc],      as1 = att_s[n0 + 16 + cc];
    float as2 = att_s[n0 + 32 + cc], as3 = att_s[n0 + 48 + cc];
    float ad0 = att_d[n0 + cc],      ad1 = att_d[n0 + 16 + cc];
    float ad2 = att_d[n0 + 32 + cc], ad3 = att_d[n0 + 48 + cc];
#pragma unroll
    for (int r = 0; r < 4; ++r) {
        int row = mbase + quad * 4 + r;
        __bf16* orow = h + (size_t)row * OUT_DIM + n0 + cc;
        orow[0]  = (__bf16)acc0[r];
        orow[16] = (__bf16)acc1[r];
        orow[32] = (__bf16)acc2[r];
        orow[48] = (__bf16)acc3[r];
        float pS = acc0[r] * as0 + acc1[r] * as1 + acc2[r] * as2 + acc3[r] * as3;
        float pD = acc0[r] * ad0 + acc1[r] * ad1 + acc2[r] * ad2 + acc3[r] * ad3;
#pragma unroll
        for (int o = 8; o >= 1; o >>= 1) {
            pS += __shfl_xor(pS, o, 64);
            pD += __shfl_xor(pD, o, 64);
        }
        if (cc == 0) {
            a_src[row * 4 + wave] = pS;
            a_dst[row * 4 + wave] = pD;
        }
    }
}

// extract chunk c of 2E elements + dst histogram
__device__ __forceinline__ void do_ext(
        int c, int njobs, const int* __restrict__ ei, bool is64,
        int* __restrict__ src32, int* __restrict__ dst32, int* __restrict__ counts, int t) {
    for (int i = c * 256 + t; i < 2 * N_EDGES; i += njobs * 256) {
        int v = is64 ? (int)((const long long*)ei)[i] : ei[i];
        if (i < N_EDGES) src32[i] = v;
        else { dst32[i - N_EDGES] = v; atomicAdd(&counts[v], 1); }
    }
}

// per-node softmax + aggregate (one wave; lds = this wave's [MAXD][4] region)
__device__ __forceinline__ void do_agg(
        int node, const __bf16* __restrict__ h,
        const float* __restrict__ a_src, const float* __restrict__ a_dst,
        const int* __restrict__ offsets, const int* __restrict__ csr_src,
        const float* __restrict__ bias, float* __restrict__ out,
        float (*lds)[4], int lane) {
    int base = offsets[node];
    int deg  = offsets[node + 1] - base;
    const float4* as4 = (const float4*)a_src;
    float4 ad = ((const float4*)a_dst)[node];

    float4 mx = {-1e30f, -1e30f, -1e30f, -1e30f};
    for (int e = lane; e < deg; e += 64) {
        int s = csr_src[base + e];
        float4 av = as4[s];
        float4 l;
        l.x = av.x + ad.x; l.x = l.x > 0.f ? l.x : NEG_SLOPE * l.x;
        l.y = av.y + ad.y; l.y = l.y > 0.f ? l.y : NEG_SLOPE * l.y;
        l.z = av.z + ad.z; l.z = l.z > 0.f ? l.z : NEG_SLOPE * l.z;
        l.w = av.w + ad.w; l.w = l.w > 0.f ? l.w : NEG_SLOPE * l.w;
        if (e < MAXD) { lds[e][0] = l.x; lds[e][1] = l.y; lds[e][2] = l.z; lds[e][3] = l.w; }
        mx.x = fmaxf(mx.x, l.x); mx.y = fmaxf(mx.y, l.y);
        mx.z = fmaxf(mx.z, l.z); mx.w = fmaxf(mx.w, l.w);
    }
#pragma unroll
    for (int o = 32; o >= 1; o >>= 1) {
        mx.x = fmaxf(mx.x, __shfl_xor(mx.x, o, 64));
        mx.y = fmaxf(mx.y, __shfl_xor(mx.y, o, 64));
        mx.z = fmaxf(mx.z, __shfl_xor(mx.z, o, 64));
        mx.w = fmaxf(mx.w, __shfl_xor(mx.w, o, 64));
    }

    float4 smv = {0.f, 0.f, 0.f, 0.f};
    for (int e = lane; e < deg; e += 64) {
        float4 l;
        if (e < MAXD) { l.x = lds[e][0]; l.y = lds[e][1]; l.z = lds[e][2]; l.w = lds[e][3]; }
        else {
            int s = csr_src[base + e];
            float4 av = as4[s];
            l.x = av.x + ad.x; l.x = l.x > 0.f ? l.x : NEG_SLOPE * l.x;
            l.y = av.y + ad.y; l.y = l.y > 0.f ? l.y : NEG_SLOPE * l.y;
            l.z = av.z + ad.z; l.z = l.z > 0.f ? l.z : NEG_SLOPE * l.z;
            l.w = av.w + ad.w; l.w = l.w > 0.f ? l.w : NEG_SLOPE * l.w;
        }
        float4 e4;
        e4.x = __expf(l.x - mx.x); e4.y = __expf(l.y - mx.y);
        e4.z = __expf(l.z - mx.z); e4.w = __expf(l.w - mx.w);
        smv.x += e4.x; smv.y += e4.y; smv.z += e4.z; smv.w += e4.w;
        if (e < MAXD) { lds[e][0] = e4.x; lds[e][1] = e4.y; lds[e][2] = e4.z; lds[e][3] = e4.w; }
    }
    int padEnd = (deg + 3) & ~3;
    if (padEnd > MAXD) padEnd = MAXD;
    for (int e = deg + lane; e < padEnd; e += 64) {
        lds[e][0] = 0.f; lds[e][1] = 0.f; lds[e][2] = 0.f; lds[e][3] = 0.f;
    }
#pragma unroll
    for (int o = 32; o >= 1; o >>= 1) {
        smv.x += __shfl_xor(smv.x, o, 64);
        smv.y += __shfl_xor(smv.y, o, 64);
        smv.z += __shfl_xor(smv.z, o, 64);
        smv.w += __shfl_xor(smv.w, o, 64);
    }

    int head = lane >> 4;
    float mh  = head == 0 ? mx.x  : head == 1 ? mx.y  : head == 2 ? mx.z  : mx.w;
    float smh = head == 0 ? smv.x : head == 1 ? smv.y : head == 2 ? smv.z : smv.w;
    float adh = head == 0 ? ad.x  : head == 1 ? ad.y  : head == 2 ? ad.z  : ad.w;
    float inv_d = 1.f / smh;

    float acc0 = 0.f, acc1 = 0.f, acc2 = 0.f, acc3 = 0.f;
    const unsigned short* hs = reinterpret_cast<const unsigned short*>(h);
    int degc = deg < MAXD ? deg : MAXD;
    int rEnd = (degc + 3) & ~3;
    for (int e = 0; e < rEnd; e += 4) {
        int s0 = csr_src[base + e];
        int s1 = csr_src[base + ((e + 1 < deg) ? e + 1 : 0)];
        int s2 = csr_src[base + ((e + 2 < deg) ? e + 2 : 0)];
        int s3 = csr_src[base + ((e + 3 < deg) ? e + 3 : 0)];
        float al0 = lds[e][head];
        float al1 = lds[e + 1][head];
        float al2 = lds[e + 2][head];
        float al3 = lds[e + 3][head];
        ushort4 h0 = *(const ushort4*)(hs + (size_t)s0 * OUT_DIM + lane * 4);
        ushort4 h1 = *(const ushort4*)(hs + (size_t)s1 * OUT_DIM + lane * 4);
        ushort4 h2 = *(const ushort4*)(hs + (size_t)s2 * OUT_DIM + lane * 4);
        ushort4 h3 = *(const ushort4*)(hs + (size_t)s3 * OUT_DIM + lane * 4);
        acc0 += al0 * b2f(h0.x) + al1 * b2f(h1.x) + al2 * b2f(h2.x) + al3 * b2f(h3.x);
        acc1 += al0 * b2f(h0.y) + al1 * b2f(h1.y) + al2 * b2f(h2.y) + al3 * b2f(h3.y);
        acc2 += al0 * b2f(h0.z) + al1 * b2f(h1.z) + al2 * b2f(h2.z) + al3 * b2f(h3.z);
        acc3 += al0 * b2f(h0.w) + al1 * b2f(h1.w) + al2 * b2f(h2.w) + al3 * b2f(h3.w);
    }
    for (int e = MAXD; e < deg; ++e) {
        int s = csr_src[base + e];
        float a = a_src[s * 4 + head] + adh;
        a = a > 0.f ? a : NEG_SLOPE * a;
        float al = __expf(a - mh);
        ushort4 hv = *(const ushort4*)(hs + (size_t)s * OUT_DIM + lane * 4);
        acc0 += al * b2f(hv.x); acc1 += al * b2f(hv.y);
        acc2 += al * b2f(hv.z); acc3 += al * b2f(hv.w);
    }

    float4 bv = ((const float4*)bias)[lane];
    float v0 = acc0 * inv_d + bv.x;
    float v1 = acc1 * inv_d + bv.y;
    float v2 = acc2 * inv_d + bv.z;
    float v3 = acc3 * inv_d + bv.w;
    float4 o4;
    o4.x = v0 > 0.f ? v0 : 0.f;
    o4.y = v1 > 0.f ? v1 : 0.f;
    o4.z = v2 > 0.f ? v2 : 0.f;
    o4.w = v3 > 0.f ? v3 : 0.f;
    ((float4*)out)[(size_t)node * 64 + lane] = o4;
}

struct Args {
    const float* x; const int* ei; const float* W;
    const float* att_s; const float* att_d; const float* bias;
    float* out;
    __bf16* Wt; __bf16* h; float* a_src; float* a_dst;
    int* counts; int* loc; int* bsum; int* bpref;
    int* offsets; int* cursor; int* csr_src; int* src32; int* dst32;
};

// ======================= cooperative mega kernel ============================
__global__ __launch_bounds__(256, 4) void mega(Args A) {
    __shared__ union { float agg[4][MAXD][4]; int scan[256]; } sm;
    cg::grid_group grid = cg::this_grid();
    const int t = threadIdx.x;
    const int b = blockIdx.x;
    const int wave = t >> 6, lane = t & 63;

    // phase 0: zero counts + W[k][n] -> Wt[n][k] bf16
    for (int i = b * 256 + t; i < N_NODES; i += GRID * 256) A.counts[i] = 0;
    for (int i = b * 256 + t; i < IN_DIM * OUT_DIM; i += GRID * 256) {
        int n = i >> 8, k = i & 255;
        A.Wt[i] = (__bf16)A.W[(size_t)k * OUT_DIM + n];
    }
    __threadfence();
    grid.sync();

    // phase 1: GEMM (3125 jobs of 16 rows) || extract+hist (375 jobs)
    for (int j = b; j < TOTAL_JOBS; j += GRID) {
        if (j < GEMM_JOBS) {
            do_gemm16(j, A.x, A.Wt, A.att_s, A.att_d, A.h, A.a_src, A.a_dst, wave, lane);
        } else {
            bool is64 = detect64(A.ei, t);
            do_ext(j - GEMM_JOBS, EXT_JOBS, A.ei, is64, A.src32, A.dst32, A.counts, t);
        }
    }
    __threadfence();
    grid.sync();

    // phase 2: per-chunk scan (49 nodes/chunk, 1024 chunks)
    for (int cb = b; cb < NCHUNK; cb += GRID) {
        if (t < 64) {
            int node = cb * CHN + t;
            int valid = (t < CHN) && (node < N_NODES);
            int cval = valid ? A.counts[node] + 1 : 0;   // +1 = self loop
            int v = cval;
#pragma unroll
            for (int off = 1; off < 64; off <<= 1) {
                int u = __shfl_up(v, off, 64);
                if (t >= off) v += u;
            }
            if (valid) A.loc[node] = v - cval;
            if (t == 63) A.bsum[cb] = v;
        }
    }
    __threadfence();
    grid.sync();

    // phase 3: scan of 1024 chunk sums (block 0)
    if (b == 0) {
        int base = t * 4;
        int s0 = A.bsum[base], s1 = A.bsum[base + 1];
        int s2 = A.bsum[base + 2], s3 = A.bsum[base + 3];
        int tsum = s0 + s1 + s2 + s3;
        sm.scan[t] = tsum;
        __syncthreads();
        for (int off = 1; off < 256; off <<= 1) {
            int u = (t >= off) ? sm.scan[t - off] : 0;
            __syncthreads();
            sm.scan[t] += u;
            __syncthreads();
        }
        int excl = sm.scan[t] - tsum;
        A.bpref[base]     = excl;
        A.bpref[base + 1] = excl + s0;
        A.bpref[base + 2] = excl + s0 + s1;
        A.bpref[base + 3] = excl + s0 + s1 + s2;
        if (t == 255) A.offsets[N_NODES] = sm.scan[t];
    }
    __threadfence();
    grid.sync();

    // phase 4: apply scan -> offsets / cursor
    for (int i = b * 256 + t; i < N_NODES; i += GRID * 256) {
        int o = A.loc[i] + A.bpref[i / CHN];
        A.offsets[i] = o;
        A.cursor[i] = o;
    }
    __threadfence();
    grid.sync();

    // phase 5: fill CSR
    for (int i = b * 256 + t; i < TOT_EDGES; i += GRID * 256) {
        if (i < N_EDGES) {
            int pos = atomicAdd(&A.cursor[A.dst32[i]], 1);
            A.csr_src[pos] = A.src32[i];
        } else {
            int n = i - N_EDGES;
            int pos = atomicAdd(&A.cursor[n], 1);
            A.csr_src[pos] = n;
        }
    }
    __threadfence();
    grid.sync();

    // phase 6: softmax + aggregate
    for (int g = b; g < AGG_JOBS; g += GRID) {
        do_agg(g * 4 + wave, A.h, A.a_src, A.a_dst, A.offsets, A.csr_src,
               A.bias, A.out, sm.agg[wave], lane);
    }
}

// ======================= fallback multi-kernel path =========================
__global__ void k_prep(Args A) {
    int i = blockIdx.x * blockDim.x + threadIdx.x;
    for (int j = i; j < N_NODES; j += gridDim.x * blockDim.x) A.counts[j] = 0;
    for (int j = i; j < IN_DIM * OUT_DIM; j += gridDim.x * blockDim.x) {
        int n = j >> 8, k = j & 255;
        A.Wt[j] = (__bf16)A.W[(size_t)k * OUT_DIM + n];
    }
}

__global__ void k_extract_hist(Args A) {
    bool is64 = detect64(A.ei, threadIdx.x);
    int i = blockIdx.x * blockDim.x + threadIdx.x;
    if (i >= 2 * N_EDGES) return;
    int v = is64 ? (int)((const long long*)A.ei)[i] : A.ei[i];
    if (i < N_EDGES) A.src32[i] = v;
    else { A.dst32[i - N_EDGES] = v; atomicAdd(&A.counts[v], 1); }
}

__global__ __launch_bounds__(256) void k_gemm16(Args A) {
    do_gemm16(blockIdx.x, A.x, A.Wt, A.att_s, A.att_d, A.h, A.a_src, A.a_dst,
              threadIdx.x >> 6, threadIdx.x & 63);
}

#define SBLK 1024
#define NBLK ((N_NODES + SBLK - 1) / SBLK)   // 49
__global__ __launch_bounds__(1024) void k_scanA(Args A) {
    __shared__ int s[SBLK];
    int t = threadIdx.x, idx = blockIdx.x * SBLK + t;
    int cval = (idx < N_NODES) ? A.counts[idx] + 1 : 0;
    s[t] = cval;
    __syncthreads();
    for (int off = 1; off < SBLK; off <<= 1) {
        int v = (t >= off) ? s[t - off] : 0;
        __syncthreads();
        s[t] += v;
        __syncthreads();
    }
    if (idx < N_NODES) A.loc[idx] = s[t] - cval;
    if (t == SBLK - 1) A.bsum[blockIdx.x] = s[t];
}

__global__ void k_scanB(Args A) {
    int lane = threadIdx.x;  // 64
    int v = (lane < NBLK) ? A.bsum[lane] : 0;
    int orig = v;
#pragma unroll
    for (int off = 1; off < 64; off <<= 1) {
        int u = __shfl_up(v, off, 64);
        if (lane >= off) v += u;
    }
    if (lane < NBLK) A.bpref[lane] = v - orig;
    if (lane == 0) A.offsets[N_NODES] = TOT_EDGES;
}

__global__ void k_scanC(Args A) {
    int idx = blockIdx.x * blockDim.x + threadIdx.x;
    if (idx < N_NODES) {
        int o = A.loc[idx] + A.bpref[idx >> 10];
        A.offsets[idx] = o;
        A.cursor[idx] = o;
    }
}

__global__ void k_fill(Args A) {
    int i = blockIdx.x * blockDim.x + threadIdx.x;
    if (i < N_EDGES) {
        int pos = atomicAdd(&A.cursor[A.dst32[i]], 1);
        A.csr_src[pos] = A.src32[i];
    } else if (i < TOT_EDGES) {
        int n = i - N_EDGES;
        int pos = atomicAdd(&A.cursor[n], 1);
        A.csr_src[pos] = n;
    }
}

__global__ __launch_bounds__(256) void k_agg(Args A) {
    __shared__ float lds[4][MAXD][4];
    int wave = threadIdx.x >> 6, lane = threadIdx.x & 63;
    int node = blockIdx.x * 4 + wave;
    if (node >= N_NODES) return;
    do_agg(node, A.h, A.a_src, A.a_dst, A.offsets, A.csr_src, A.bias, A.out,
           lds[wave], lane);
}

// ---------------------------------------------------------------------------
extern "C" void kernel_launch(void* const* d_in, const int* in_sizes, int n_in,
                              void* d_out, int out_size, void* d_ws, size_t ws_size,
                              hipStream_t stream) {
    (void)out_size; (void)ws_size;
    const void* p_x = nullptr; const void* p_ei = nullptr; const void* p_W = nullptr;
    const void* p_small[3] = {nullptr, nullptr, nullptr}; int nsmall = 0;
    for (int i = 0; i < n_in; ++i) {
        switch (in_sizes[i]) {
            case N_NODES * IN_DIM:      p_x = d_in[i]; break;
            case 2 * N_EDGES:           p_ei = d_in[i]; break;
            case IN_DIM * OUT_DIM:      p_W = d_in[i]; break;
            case OUT_DIM:               if (nsmall < 3) p_small[nsmall++] = d_in[i]; break;
            default: break;
        }
    }
    if (!p_x)  p_x  = d_in[0];
    if (!p_ei) p_ei = d_in[1];
    if (!p_W)  p_W  = d_in[2];
    if (nsmall < 3) { p_small[0] = d_in[3]; p_small[1] = d_in[4]; p_small[2] = d_in[5]; }

    char* ws = (char*)d_ws;
    size_t off = 0;
    auto alloc = [&](size_t bytes) -> void* {
        void* p = ws + off;
        off = (off + bytes + 255) & ~(size_t)255;
        return p;
    };
    Args A;
    A.Wt      = (__bf16*)alloc((size_t)IN_DIM * OUT_DIM * 2);
    A.h       = (__bf16*)alloc((size_t)N_NODES * OUT_DIM * 2);
    A.a_src   = (float*)alloc((size_t)N_NODES * HEADS * 4);
    A.a_dst   = (float*)alloc((size_t)N_NODES * HEADS * 4);
    A.counts  = (int*)alloc((size_t)N_NODES * 4);
    A.loc     = (int*)alloc((size_t)N_NODES * 4);
    A.bsum    = (int*)alloc(NCHUNK * 4);
    A.bpref   = (int*)alloc(NCHUNK * 4);
    A.offsets = (int*)alloc((size_t)(N_NODES + 1) * 4);
    A.cursor  = (int*)alloc((size_t)N_NODES * 4);
    A.csr_src = (int*)alloc((size_t)TOT_EDGES * 4);
    A.src32   = (int*)alloc((size_t)N_EDGES * 4);
    A.dst32   = (int*)alloc((size_t)N_EDGES * 4);

    A.x     = (const float*)p_x;
    A.ei    = (const int*)p_ei;
    A.W     = (const float*)p_W;
    A.att_s = (const float*)p_small[0];
    A.att_d = (const float*)p_small[1];
    A.bias  = (const float*)p_small[2];
    A.out   = (float*)d_out;

    void* params[] = { (void*)&A };
    hipError_t err = hipLaunchCooperativeKernel(
        reinterpret_cast<void*>(mega), dim3(GRID), dim3(256), params, 0, stream);
    if (err != hipSuccess) {
        // fallback: proven multi-kernel pipeline (same device functions)
        k_prep<<<dim3(512), dim3(256), 0, stream>>>(A);
        k_extract_hist<<<dim3((2 * N_EDGES + 255) / 256), dim3(256), 0, stream>>>(A);
        k_gemm16<<<dim3(GEMM_JOBS), dim3(256), 0, stream>>>(A);
        k_scanA<<<dim3(NBLK), dim3(SBLK), 0, stream>>>(A);
        k_scanB<<<dim3(1), dim3(64), 0, stream>>>(A);
        k_scanC<<<dim3((N_NODES + 255) / 256), dim3(256), 0, stream>>>(A);
        k_fill<<<dim3((TOT_EDGES + 255) / 256), dim3(256), 0, stream>>>(A);
        k_agg<<<dim3((N_NODES + 3) / 4), dim3(256), 0, stream>>>(A);
    }
}

// Round 7
// 332.792 us; speedup vs baseline: 4.4581x; 4.4581x over previous
//
#include <hip/hip_runtime.h>
#include <hip/hip_bf16.h>

#define N_NODES 50000
#define N_EDGES 800000
#define TOT_EDGES (N_EDGES + N_NODES)
#define IN_DIM 256
#define OUT_DIM 256   // HEADS * HID
#define HEADS 4
#define NEG_SLOPE 0.2f
#define MAXD 128      // LDS alpha-cache per node
#define GEMM_JOBS 3125 // 16 rows each = 50000

typedef __bf16 bf16x8 __attribute__((ext_vector_type(8)));
typedef float f32x4 __attribute__((ext_vector_type(4)));

__device__ __forceinline__ float b2f(unsigned short u) {
    union { float f; unsigned int i; } v; v.i = ((unsigned int)u) << 16; return v.f;
}

// block-uniform int64-vs-int32 detection (all threads of block must call)
__device__ __forceinline__ bool detect64(const int* __restrict__ ei, int t) {
    int nz = 0;
    for (int i = t; i < 1024; i += 256)
        if (ei[2 * i + 1] != 0) nz++;
    return __syncthreads_count(nz) == 0;
}

struct Args {
    const float* x; const int* ei; const float* W;
    const float* att_s; const float* att_d; const float* bias;
    float* out;
    __bf16* Wt; __bf16* h; float* a_src; float* a_dst;
    int* counts; int* loc; int* bsum; int* bpref;
    int* offsets; int* cursor; int* csr_src;
};

// ---------------- K_front: Wt transpose + dst histogram ---------------------
// grid-stride over both jobs; counts pre-zeroed by memset
__global__ __launch_bounds__(256) void k_front(Args A) {
    bool is64 = detect64(A.ei, threadIdx.x);
    int gid = blockIdx.x * 256 + threadIdx.x;
    int gsz = gridDim.x * 256;
    for (int i = gid; i < IN_DIM * OUT_DIM; i += gsz) {
        int n = i >> 8, k = i & 255;
        A.Wt[i] = (__bf16)A.W[(size_t)k * OUT_DIM + n];
    }
    const long long* ei64 = (const long long*)A.ei;
    for (int i = gid; i < N_EDGES; i += gsz) {
        int v = is64 ? (int)ei64[N_EDGES + i] : A.ei[N_EDGES + i];
        atomicAdd(&A.counts[v], 1);
    }
}

// ---------------- K_gemm16: 16 rows/block, fused attention logits -----------
__global__ __launch_bounds__(256) void k_gemm16(Args A) {
    const int wave = threadIdx.x >> 6;
    const int lane = threadIdx.x & 63;
    const int cc   = lane & 15;
    const int quad = lane >> 4;
    const int mbase = blockIdx.x * 16;
    const int n0    = wave * 64;
    f32x4 acc0 = {0.f, 0.f, 0.f, 0.f};
    f32x4 acc1 = acc0, acc2 = acc0, acc3 = acc0;
    const float4* x4 = (const float4*)A.x;
    const int arow = mbase + cc;
    for (int k0 = 0; k0 < IN_DIM; k0 += 32) {
        bf16x8 b0 = *(const bf16x8*)(A.Wt + (size_t)(n0 + cc)      * IN_DIM + k0 + quad * 8);
        bf16x8 b1 = *(const bf16x8*)(A.Wt + (size_t)(n0 + 16 + cc) * IN_DIM + k0 + quad * 8);
        bf16x8 b2 = *(const bf16x8*)(A.Wt + (size_t)(n0 + 32 + cc) * IN_DIM + k0 + quad * 8);
        bf16x8 b3 = *(const bf16x8*)(A.Wt + (size_t)(n0 + 48 + cc) * IN_DIM + k0 + quad * 8);
        float4 lo = x4[(size_t)arow * 64 + (k0 >> 2) + quad * 2];
        float4 hi = x4[(size_t)arow * 64 + (k0 >> 2) + quad * 2 + 1];
        bf16x8 a;
        a[0] = (__bf16)lo.x; a[1] = (__bf16)lo.y; a[2] = (__bf16)lo.z; a[3] = (__bf16)lo.w;
        a[4] = (__bf16)hi.x; a[5] = (__bf16)hi.y; a[6] = (__bf16)hi.z; a[7] = (__bf16)hi.w;
        acc0 = __builtin_amdgcn_mfma_f32_16x16x32_bf16(a, b0, acc0, 0, 0, 0);
        acc1 = __builtin_amdgcn_mfma_f32_16x16x32_bf16(a, b1, acc1, 0, 0, 0);
        acc2 = __builtin_amdgcn_mfma_f32_16x16x32_bf16(a, b2, acc2, 0, 0, 0);
        acc3 = __builtin_amdgcn_mfma_f32_16x16x32_bf16(a, b3, acc3, 0, 0, 0);
    }
    float as0 = A.att_s[n0 + cc],      as1 = A.att_s[n0 + 16 + cc];
    float as2 = A.att_s[n0 + 32 + cc], as3 = A.att_s[n0 + 48 + cc];
    float ad0 = A.att_d[n0 + cc],      ad1 = A.att_d[n0 + 16 + cc];
    float ad2 = A.att_d[n0 + 32 + cc], ad3 = A.att_d[n0 + 48 + cc];
#pragma unroll
    for (int r = 0; r < 4; ++r) {
        int row = mbase + quad * 4 + r;
        __bf16* orow = A.h + (size_t)row * OUT_DIM + n0 + cc;
        orow[0]  = (__bf16)acc0[r];
        orow[16] = (__bf16)acc1[r];
        orow[32] = (__bf16)acc2[r];
        orow[48] = (__bf16)acc3[r];
        float pS = acc0[r] * as0 + acc1[r] * as1 + acc2[r] * as2 + acc3[r] * as3;
        float pD = acc0[r] * ad0 + acc1[r] * ad1 + acc2[r] * ad2 + acc3[r] * ad3;
#pragma unroll
        for (int o = 8; o >= 1; o >>= 1) {
            pS += __shfl_xor(pS, o, 64);
            pD += __shfl_xor(pD, o, 64);
        }
        if (cc == 0) {
            A.a_src[row * 4 + wave] = pS;
            A.a_dst[row * 4 + wave] = pD;
        }
    }
}

// ---------------- scan (3 kernels, coalesced) -------------------------------
#define SBLK 1024
#define NBLK ((N_NODES + SBLK - 1) / SBLK)   // 49
__global__ __launch_bounds__(1024) void k_scanA(Args A) {
    __shared__ int s[SBLK];
    int t = threadIdx.x, idx = blockIdx.x * SBLK + t;
    int cval = (idx < N_NODES) ? A.counts[idx] + 1 : 0;   // +1 = self loop
    s[t] = cval;
    __syncthreads();
    for (int off = 1; off < SBLK; off <<= 1) {
        int v = (t >= off) ? s[t - off] : 0;
        __syncthreads();
        s[t] += v;
        __syncthreads();
    }
    if (idx < N_NODES) A.loc[idx] = s[t] - cval;
    if (t == SBLK - 1) A.bsum[blockIdx.x] = s[t];
}

__global__ void k_scanB(Args A) {
    int lane = threadIdx.x;  // 64
    int v = (lane < NBLK) ? A.bsum[lane] : 0;
    int orig = v;
#pragma unroll
    for (int off = 1; off < 64; off <<= 1) {
        int u = __shfl_up(v, off, 64);
        if (lane >= off) v += u;
    }
    if (lane < NBLK) A.bpref[lane] = v - orig;
    if (lane == 0) A.offsets[N_NODES] = TOT_EDGES;
}

__global__ void k_scanC(Args A) {
    int idx = blockIdx.x * blockDim.x + threadIdx.x;
    if (idx < N_NODES) {
        int o = A.loc[idx] + A.bpref[idx >> 10];
        A.offsets[idx] = o;
        A.cursor[idx] = o;
    }
}

// ---------------- K_fill: CSR fill, reads ei directly -----------------------
__global__ __launch_bounds__(256) void k_fill(Args A) {
    bool is64 = detect64(A.ei, threadIdx.x);
    int i = blockIdx.x * blockDim.x + threadIdx.x;
    const long long* ei64 = (const long long*)A.ei;
    if (i < N_EDGES) {
        int s, d;
        if (is64) { s = (int)ei64[i]; d = (int)ei64[N_EDGES + i]; }
        else      { s = A.ei[i];      d = A.ei[N_EDGES + i]; }
        int pos = atomicAdd(&A.cursor[d], 1);
        A.csr_src[pos] = s;
    } else if (i < TOT_EDGES) {
        int n = i - N_EDGES;
        int pos = atomicAdd(&A.cursor[n], 1);
        A.csr_src[pos] = n;
    }
}

// ---------------- K_agg: 2-pass softmax (no max) + aggregation --------------
__global__ __launch_bounds__(256) void k_agg(Args A) {
    __shared__ float lds_all[4][MAXD][4];
    int wave = threadIdx.x >> 6, lane = threadIdx.x & 63;
    int node = blockIdx.x * 4 + wave;
    if (node >= N_NODES) return;
    float (*lds)[4] = lds_all[wave];

    int base = A.offsets[node];
    int deg  = A.offsets[node + 1] - base;
    const float4* as4 = (const float4*)A.a_src;
    float4 ad = ((const float4*)A.a_dst)[node];

    // pass A: alpha = exp(leaky(a_src+a_dst)) -> LDS, running sum
    // (max subtraction skipped: |logit| <= ~10 << 88, exp cannot overflow)
    float4 smv = {0.f, 0.f, 0.f, 0.f};
    for (int e = lane; e < deg; e += 64) {
        int s = A.csr_src[base + e];
        float4 av = as4[s];
        float4 l;
        l.x = av.x + ad.x; l.x = l.x > 0.f ? l.x : NEG_SLOPE * l.x;
        l.y = av.y + ad.y; l.y = l.y > 0.f ? l.y : NEG_SLOPE * l.y;
        l.z = av.z + ad.z; l.z = l.z > 0.f ? l.z : NEG_SLOPE * l.z;
        l.w = av.w + ad.w; l.w = l.w > 0.f ? l.w : NEG_SLOPE * l.w;
        float4 e4;
        e4.x = __expf(l.x); e4.y = __expf(l.y);
        e4.z = __expf(l.z); e4.w = __expf(l.w);
        smv.x += e4.x; smv.y += e4.y; smv.z += e4.z; smv.w += e4.w;
        if (e < MAXD) { lds[e][0] = e4.x; lds[e][1] = e4.y; lds[e][2] = e4.z; lds[e][3] = e4.w; }
    }
    int padEnd = (deg + 3) & ~3;
    if (padEnd > MAXD) padEnd = MAXD;
    for (int e = deg + lane; e < padEnd; e += 64) {
        lds[e][0] = 0.f; lds[e][1] = 0.f; lds[e][2] = 0.f; lds[e][3] = 0.f;
    }
#pragma unroll
    for (int o = 32; o >= 1; o >>= 1) {
        smv.x += __shfl_xor(smv.x, o, 64);
        smv.y += __shfl_xor(smv.y, o, 64);
        smv.z += __shfl_xor(smv.z, o, 64);
        smv.w += __shfl_xor(smv.w, o, 64);
    }

    int head = lane >> 4;
    float smh = head == 0 ? smv.x : head == 1 ? smv.y : head == 2 ? smv.z : smv.w;
    float adh = head == 0 ? ad.x  : head == 1 ? ad.y  : head == 2 ? ad.z  : ad.w;
    float inv_d = 1.f / smh;

    // pass B: unroll-by-4 gather + FMA (alpha from LDS)
    float acc0 = 0.f, acc1 = 0.f, acc2 = 0.f, acc3 = 0.f;
    const unsigned short* hs = reinterpret_cast<const unsigned short*>(A.h);
    int degc = deg < MAXD ? deg : MAXD;
    int rEnd = (degc + 3) & ~3;
    for (int e = 0; e < rEnd; e += 4) {
        int s0 = A.csr_src[base + e];
        int s1 = A.csr_src[base + ((e + 1 < deg) ? e + 1 : 0)];
        int s2 = A.csr_src[base + ((e + 2 < deg) ? e + 2 : 0)];
        int s3 = A.csr_src[base + ((e + 3 < deg) ? e + 3 : 0)];
        float al0 = lds[e][head];
        float al1 = lds[e + 1][head];
        float al2 = lds[e + 2][head];
        float al3 = lds[e + 3][head];
        ushort4 h0 = *(const ushort4*)(hs + (size_t)s0 * OUT_DIM + lane * 4);
        ushort4 h1 = *(const ushort4*)(hs + (size_t)s1 * OUT_DIM + lane * 4);
        ushort4 h2 = *(const ushort4*)(hs + (size_t)s2 * OUT_DIM + lane * 4);
        ushort4 h3 = *(const ushort4*)(hs + (size_t)s3 * OUT_DIM + lane * 4);
        acc0 += al0 * b2f(h0.x) + al1 * b2f(h1.x) + al2 * b2f(h2.x) + al3 * b2f(h3.x);
        acc1 += al0 * b2f(h0.y) + al1 * b2f(h1.y) + al2 * b2f(h2.y) + al3 * b2f(h3.y);
        acc2 += al0 * b2f(h0.z) + al1 * b2f(h1.z) + al2 * b2f(h2.z) + al3 * b2f(h3.z);
        acc3 += al0 * b2f(h0.w) + al1 * b2f(h1.w) + al2 * b2f(h2.w) + al3 * b2f(h3.w);
    }
    // rare tail: deg > MAXD -> recompute alpha
    for (int e = MAXD; e < deg; ++e) {
        int s = A.csr_src[base + e];
        float a = A.a_src[s * 4 + head] + adh;
        a = a > 0.f ? a : NEG_SLOPE * a;
        float al = __expf(a);
        ushort4 hv = *(const ushort4*)(hs + (size_t)s * OUT_DIM + lane * 4);
        acc0 += al * b2f(hv.x); acc1 += al * b2f(hv.y);
        acc2 += al * b2f(hv.z); acc3 += al * b2f(hv.w);
    }

    float4 bv = ((const float4*)A.bias)[lane];
    float v0 = acc0 * inv_d + bv.x;
    float v1 = acc1 * inv_d + bv.y;
    float v2 = acc2 * inv_d + bv.z;
    float v3 = acc3 * inv_d + bv.w;
    float4 o4;
    o4.x = v0 > 0.f ? v0 : 0.f;
    o4.y = v1 > 0.f ? v1 : 0.f;
    o4.z = v2 > 0.f ? v2 : 0.f;
    o4.w = v3 > 0.f ? v3 : 0.f;
    ((float4*)A.out)[(size_t)node * 64 + lane] = o4;
}

// ---------------------------------------------------------------------------
extern "C" void kernel_launch(void* const* d_in, const int* in_sizes, int n_in,
                              void* d_out, int out_size, void* d_ws, size_t ws_size,
                              hipStream_t stream) {
    (void)out_size; (void)ws_size;
    const void* p_x = nullptr; const void* p_ei = nullptr; const void* p_W = nullptr;
    const void* p_small[3] = {nullptr, nullptr, nullptr}; int nsmall = 0;
    for (int i = 0; i < n_in; ++i) {
        switch (in_sizes[i]) {
            case N_NODES * IN_DIM:      p_x = d_in[i]; break;
            case 2 * N_EDGES:           p_ei = d_in[i]; break;
            case IN_DIM * OUT_DIM:      p_W = d_in[i]; break;
            case OUT_DIM:               if (nsmall < 3) p_small[nsmall++] = d_in[i]; break;
            default: break;
        }
    }
    if (!p_x)  p_x  = d_in[0];
    if (!p_ei) p_ei = d_in[1];
    if (!p_W)  p_W  = d_in[2];
    if (nsmall < 3) { p_small[0] = d_in[3]; p_small[1] = d_in[4]; p_small[2] = d_in[5]; }

    char* ws = (char*)d_ws;
    size_t off = 0;
    auto alloc = [&](size_t bytes) -> void* {
        void* p = ws + off;
        off = (off + bytes + 255) & ~(size_t)255;
        return p;
    };
    Args A;
    A.Wt      = (__bf16*)alloc((size_t)IN_DIM * OUT_DIM * 2);
    A.h       = (__bf16*)alloc((size_t)N_NODES * OUT_DIM * 2);
    A.a_src   = (float*)alloc((size_t)N_NODES * HEADS * 4);
    A.a_dst   = (float*)alloc((size_t)N_NODES * HEADS * 4);
    A.counts  = (int*)alloc((size_t)N_NODES * 4);
    A.loc     = (int*)alloc((size_t)N_NODES * 4);
    A.bsum    = (int*)alloc(NBLK * 4);
    A.bpref   = (int*)alloc(NBLK * 4);
    A.offsets = (int*)alloc((size_t)(N_NODES + 1) * 4);
    A.cursor  = (int*)alloc((size_t)N_NODES * 4);
    A.csr_src = (int*)alloc((size_t)TOT_EDGES * 4);

    A.x     = (const float*)p_x;
    A.ei    = (const int*)p_ei;
    A.W     = (const float*)p_W;
    A.att_s = (const float*)p_small[0];
    A.att_d = (const float*)p_small[1];
    A.bias  = (const float*)p_small[2];
    A.out   = (float*)d_out;

    hipMemsetAsync(A.counts, 0, (size_t)N_NODES * 4, stream);
    k_front<<<dim3(1024), dim3(256), 0, stream>>>(A);
    k_gemm16<<<dim3(GEMM_JOBS), dim3(256), 0, stream>>>(A);
    k_scanA<<<dim3(NBLK), dim3(SBLK), 0, stream>>>(A);
    k_scanB<<<dim3(1), dim3(64), 0, stream>>>(A);
    k_scanC<<<dim3((N_NODES + 255) / 256), dim3(256), 0, stream>>>(A);
    k_fill<<<dim3((TOT_EDGES + 255) / 256), dim3(256), 0, stream>>>(A);
    k_agg<<<dim3((N_NODES + 3) / 4), dim3(256), 0, stream>>>(A);
}

// Round 8
// 289.894 us; speedup vs baseline: 5.1179x; 1.1480x over previous
//
#include <hip/hip_runtime.h>
#include <hip/hip_bf16.h>

#define N_NODES 50000
#define N_EDGES 800000
#define TOT_EDGES (N_EDGES + N_NODES)
#define IN_DIM 256
#define OUT_DIM 256   // HEADS * HID
#define HEADS 4
#define NEG_SLOPE 0.2f
#define MAXD 128      // LDS alpha-cache per node

#define GBLK 782      // gemm blocks: 64 rows each (50000 = 781*64 + 16)
#define HBLK 512      // histogram blocks
#define LDS_STRIDE 264  // 256 + 8 pad (bf16 elems) -> 2-way-free LDS banks

typedef __bf16 bf16x8 __attribute__((ext_vector_type(8)));
typedef __bf16 bf16x4 __attribute__((ext_vector_type(4)));
typedef float f32x4 __attribute__((ext_vector_type(4)));

__device__ __forceinline__ float b2f(unsigned short u) {
    union { float f; unsigned int i; } v; v.i = ((unsigned int)u) << 16; return v.f;
}

// block-uniform int64-vs-int32 detection (all threads of block must call)
__device__ __forceinline__ bool detect64(const int* __restrict__ ei, int t) {
    int nz = 0;
    for (int i = t; i < 1024; i += 256)
        if (ei[2 * i + 1] != 0) nz++;
    return __syncthreads_count(nz) == 0;
}

struct Args {
    const float* x; const int* ei; const float* W;
    const float* att_s; const float* att_d; const float* bias;
    float* out;
    __bf16* Wt; __bf16* h; float* a_src; float* a_dst;
    int* counts; int* loc; int* bsum; int* bpref;
    int* offsets; int* cursor; int* csr_src;
};

// ---------------- K_wt: W fp32 [k][n] -> Wt bf16 [n][k] ---------------------
__global__ void k_wt(Args A) {
    int k = blockIdx.x;    // 256
    int n = threadIdx.x;   // 256
    A.Wt[(size_t)n * IN_DIM + k] = (__bf16)A.W[(size_t)k * OUT_DIM + n];
}

// ---------------- K_gemm_hist: 64-row LDS-staged GEMM || dst histogram ------
__global__ __launch_bounds__(256) void k_gemm_hist(Args A) {
    __shared__ __bf16 xs[64 * LDS_STRIDE];   // 33 KB
    const int t = threadIdx.x;

    if (blockIdx.x < GBLK) {
        // ---- stage x[mbase .. mbase+64) -> bf16 LDS (coalesced float4) ----
        const int mbase = blockIdx.x * 64;
        const float4* x4 = (const float4*)A.x;
#pragma unroll
        for (int i = 0; i < 16; ++i) {
            int f = i * 256 + t;            // 0..4095 over 64 rows x 64 float4
            int row = f >> 6;
            int c4  = f & 63;
            int grow = mbase + row;
            if (grow >= N_NODES) grow = N_NODES - 1;   // clamp (last block only)
            float4 v = x4[(size_t)grow * 64 + c4];
            bf16x4 o = { (__bf16)v.x, (__bf16)v.y, (__bf16)v.z, (__bf16)v.w };
            *(bf16x4*)&xs[row * LDS_STRIDE + c4 * 4] = o;
        }
        __syncthreads();

        // ---- MFMA: 4 m-tiles x 4 n-frags, K-loop of 8 ----------------------
        const int wave = t >> 6;
        const int lane = t & 63;
        const int cc   = lane & 15;
        const int quad = lane >> 4;
        const int n0   = wave * 64;
        f32x4 acc[4][4];
#pragma unroll
        for (int mt = 0; mt < 4; ++mt)
#pragma unroll
            for (int j = 0; j < 4; ++j) acc[mt][j] = (f32x4){0.f, 0.f, 0.f, 0.f};

        for (int k0 = 0; k0 < IN_DIM; k0 += 32) {
            bf16x8 b0 = *(const bf16x8*)(A.Wt + (size_t)(n0 + cc)      * IN_DIM + k0 + quad * 8);
            bf16x8 b1 = *(const bf16x8*)(A.Wt + (size_t)(n0 + 16 + cc) * IN_DIM + k0 + quad * 8);
            bf16x8 b2 = *(const bf16x8*)(A.Wt + (size_t)(n0 + 32 + cc) * IN_DIM + k0 + quad * 8);
            bf16x8 b3 = *(const bf16x8*)(A.Wt + (size_t)(n0 + 48 + cc) * IN_DIM + k0 + quad * 8);
#pragma unroll
            for (int mt = 0; mt < 4; ++mt) {
                bf16x8 a = *(const bf16x8*)&xs[(mt * 16 + cc) * LDS_STRIDE + k0 + quad * 8];
                acc[mt][0] = __builtin_amdgcn_mfma_f32_16x16x32_bf16(a, b0, acc[mt][0], 0, 0, 0);
                acc[mt][1] = __builtin_amdgcn_mfma_f32_16x16x32_bf16(a, b1, acc[mt][1], 0, 0, 0);
                acc[mt][2] = __builtin_amdgcn_mfma_f32_16x16x32_bf16(a, b2, acc[mt][2], 0, 0, 0);
                acc[mt][3] = __builtin_amdgcn_mfma_f32_16x16x32_bf16(a, b3, acc[mt][3], 0, 0, 0);
            }
        }

        // ---- epilogue: h store + fused attention logits --------------------
        float as0 = A.att_s[n0 + cc],      as1 = A.att_s[n0 + 16 + cc];
        float as2 = A.att_s[n0 + 32 + cc], as3 = A.att_s[n0 + 48 + cc];
        float ad0 = A.att_d[n0 + cc],      ad1 = A.att_d[n0 + 16 + cc];
        float ad2 = A.att_d[n0 + 32 + cc], ad3 = A.att_d[n0 + 48 + cc];
#pragma unroll
        for (int mt = 0; mt < 4; ++mt) {
#pragma unroll
            for (int r = 0; r < 4; ++r) {
                int row = mbase + mt * 16 + quad * 4 + r;
                bool ok = row < N_NODES;
                float pS = acc[mt][0][r] * as0 + acc[mt][1][r] * as1
                         + acc[mt][2][r] * as2 + acc[mt][3][r] * as3;
                float pD = acc[mt][0][r] * ad0 + acc[mt][1][r] * ad1
                         + acc[mt][2][r] * ad2 + acc[mt][3][r] * ad3;
#pragma unroll
                for (int o = 8; o >= 1; o >>= 1) {
                    pS += __shfl_xor(pS, o, 64);
                    pD += __shfl_xor(pD, o, 64);
                }
                if (ok) {
                    __bf16* orow = A.h + (size_t)row * OUT_DIM + n0 + cc;
                    orow[0]  = (__bf16)acc[mt][0][r];
                    orow[16] = (__bf16)acc[mt][1][r];
                    orow[32] = (__bf16)acc[mt][2][r];
                    orow[48] = (__bf16)acc[mt][3][r];
                    if (cc == 0) {
                        A.a_src[row * 4 + wave] = pS;
                        A.a_dst[row * 4 + wave] = pD;
                    }
                }
            }
        }
    } else {
        // ---- dst histogram (independent of GEMM) ---------------------------
        bool is64 = detect64(A.ei, t);
        const long long* ei64 = (const long long*)A.ei;
        int bi = blockIdx.x - GBLK;
        for (int i = bi * 256 + t; i < N_EDGES; i += HBLK * 256) {
            int v = is64 ? (int)ei64[N_EDGES + i] : A.ei[N_EDGES + i];
            atomicAdd(&A.counts[v], 1);
        }
    }
}

// ---------------- scan (3 kernels, coalesced) -------------------------------
#define SBLK 1024
#define NBLK ((N_NODES + SBLK - 1) / SBLK)   // 49
__global__ __launch_bounds__(1024) void k_scanA(Args A) {
    __shared__ int s[SBLK];
    int t = threadIdx.x, idx = blockIdx.x * SBLK + t;
    int cval = (idx < N_NODES) ? A.counts[idx] + 1 : 0;   // +1 = self loop
    s[t] = cval;
    __syncthreads();
    for (int off = 1; off < SBLK; off <<= 1) {
        int v = (t >= off) ? s[t - off] : 0;
        __syncthreads();
        s[t] += v;
        __syncthreads();
    }
    if (idx < N_NODES) A.loc[idx] = s[t] - cval;
    if (t == SBLK - 1) A.bsum[blockIdx.x] = s[t];
}

__global__ void k_scanB(Args A) {
    int lane = threadIdx.x;  // 64
    int v = (lane < NBLK) ? A.bsum[lane] : 0;
    int orig = v;
#pragma unroll
    for (int off = 1; off < 64; off <<= 1) {
        int u = __shfl_up(v, off, 64);
        if (lane >= off) v += u;
    }
    if (lane < NBLK) A.bpref[lane] = v - orig;
    if (lane == 0) A.offsets[N_NODES] = TOT_EDGES;
}

__global__ void k_scanC(Args A) {
    int idx = blockIdx.x * blockDim.x + threadIdx.x;
    if (idx < N_NODES) {
        int o = A.loc[idx] + A.bpref[idx >> 10];
        A.offsets[idx] = o;
        A.cursor[idx] = o;
    }
}

// ---------------- K_fill: CSR fill, reads ei directly -----------------------
__global__ __launch_bounds__(256) void k_fill(Args A) {
    bool is64 = detect64(A.ei, threadIdx.x);
    int i = blockIdx.x * blockDim.x + threadIdx.x;
    const long long* ei64 = (const long long*)A.ei;
    if (i < N_EDGES) {
        int s, d;
        if (is64) { s = (int)ei64[i]; d = (int)ei64[N_EDGES + i]; }
        else      { s = A.ei[i];      d = A.ei[N_EDGES + i]; }
        int pos = atomicAdd(&A.cursor[d], 1);
        A.csr_src[pos] = s;
    } else if (i < TOT_EDGES) {
        int n = i - N_EDGES;
        int pos = atomicAdd(&A.cursor[n], 1);
        A.csr_src[pos] = n;
    }
}

// ---------------- K_agg: 2-pass softmax (no max) + aggregation --------------
__global__ __launch_bounds__(256) void k_agg(Args A) {
    __shared__ float lds_all[4][MAXD][4];
    int wave = threadIdx.x >> 6, lane = threadIdx.x & 63;
    int node = blockIdx.x * 4 + wave;
    if (node >= N_NODES) return;
    float (*lds)[4] = lds_all[wave];

    int base = A.offsets[node];
    int deg  = A.offsets[node + 1] - base;
    const float4* as4 = (const float4*)A.a_src;
    float4 ad = ((const float4*)A.a_dst)[node];

    // pass A: alpha = exp(leaky(a_src+a_dst)) -> LDS, running sum
    // (max subtraction skipped: |logit| <= ~10 << 88, exp cannot overflow)
    float4 smv = {0.f, 0.f, 0.f, 0.f};
    for (int e = lane; e < deg; e += 64) {
        int s = A.csr_src[base + e];
        float4 av = as4[s];
        float4 l;
        l.x = av.x + ad.x; l.x = l.x > 0.f ? l.x : NEG_SLOPE * l.x;
        l.y = av.y + ad.y; l.y = l.y > 0.f ? l.y : NEG_SLOPE * l.y;
        l.z = av.z + ad.z; l.z = l.z > 0.f ? l.z : NEG_SLOPE * l.z;
        l.w = av.w + ad.w; l.w = l.w > 0.f ? l.w : NEG_SLOPE * l.w;
        float4 e4;
        e4.x = __expf(l.x); e4.y = __expf(l.y);
        e4.z = __expf(l.z); e4.w = __expf(l.w);
        smv.x += e4.x; smv.y += e4.y; smv.z += e4.z; smv.w += e4.w;
        if (e < MAXD) { lds[e][0] = e4.x; lds[e][1] = e4.y; lds[e][2] = e4.z; lds[e][3] = e4.w; }
    }
    int padEnd = (deg + 3) & ~3;
    if (padEnd > MAXD) padEnd = MAXD;
    for (int e = deg + lane; e < padEnd; e += 64) {
        lds[e][0] = 0.f; lds[e][1] = 0.f; lds[e][2] = 0.f; lds[e][3] = 0.f;
    }
#pragma unroll
    for (int o = 32; o >= 1; o >>= 1) {
        smv.x += __shfl_xor(smv.x, o, 64);
        smv.y += __shfl_xor(smv.y, o, 64);
        smv.z += __shfl_xor(smv.z, o, 64);
        smv.w += __shfl_xor(smv.w, o, 64);
    }

    int head = lane >> 4;
    float smh = head == 0 ? smv.x : head == 1 ? smv.y : head == 2 ? smv.z : smv.w;
    float adh = head == 0 ? ad.x  : head == 1 ? ad.y  : head == 2 ? ad.z  : ad.w;
    float inv_d = 1.f / smh;

    // pass B: unroll-by-4 gather + FMA (alpha from LDS)
    float acc0 = 0.f, acc1 = 0.f, acc2 = 0.f, acc3 = 0.f;
    const unsigned short* hs = reinterpret_cast<const unsigned short*>(A.h);
    int degc = deg < MAXD ? deg : MAXD;
    int rEnd = (degc + 3) & ~3;
    for (int e = 0; e < rEnd; e += 4) {
        int s0 = A.csr_src[base + e];
        int s1 = A.csr_src[base + ((e + 1 < deg) ? e + 1 : 0)];
        int s2 = A.csr_src[base + ((e + 2 < deg) ? e + 2 : 0)];
        int s3 = A.csr_src[base + ((e + 3 < deg) ? e + 3 : 0)];
        float al0 = lds[e][head];
        float al1 = lds[e + 1][head];
        float al2 = lds[e + 2][head];
        float al3 = lds[e + 3][head];
        ushort4 h0 = *(const ushort4*)(hs + (size_t)s0 * OUT_DIM + lane * 4);
        ushort4 h1 = *(const ushort4*)(hs + (size_t)s1 * OUT_DIM + lane * 4);
        ushort4 h2 = *(const ushort4*)(hs + (size_t)s2 * OUT_DIM + lane * 4);
        ushort4 h3 = *(const ushort4*)(hs + (size_t)s3 * OUT_DIM + lane * 4);
        acc0 += al0 * b2f(h0.x) + al1 * b2f(h1.x) + al2 * b2f(h2.x) + al3 * b2f(h3.x);
        acc1 += al0 * b2f(h0.y) + al1 * b2f(h1.y) + al2 * b2f(h2.y) + al3 * b2f(h3.y);
        acc2 += al0 * b2f(h0.z) + al1 * b2f(h1.z) + al2 * b2f(h2.z) + al3 * b2f(h3.z);
        acc3 += al0 * b2f(h0.w) + al1 * b2f(h1.w) + al2 * b2f(h2.w) + al3 * b2f(h3.w);
    }
    // rare tail: deg > MAXD -> recompute alpha
    for (int e = MAXD; e < deg; ++e) {
        int s = A.csr_src[base + e];
        float a = A.a_src[s * 4 + head] + adh;
        a = a > 0.f ? a : NEG_SLOPE * a;
        float al = __expf(a);
        ushort4 hv = *(const ushort4*)(hs + (size_t)s * OUT_DIM + lane * 4);
        acc0 += al * b2f(hv.x); acc1 += al * b2f(hv.y);
        acc2 += al * b2f(hv.z); acc3 += al * b2f(hv.w);
    }

    float4 bv = ((const float4*)A.bias)[lane];
    float v0 = acc0 * inv_d + bv.x;
    float v1 = acc1 * inv_d + bv.y;
    float v2 = acc2 * inv_d + bv.z;
    float v3 = acc3 * inv_d + bv.w;
    float4 o4;
    o4.x = v0 > 0.f ? v0 : 0.f;
    o4.y = v1 > 0.f ? v1 : 0.f;
    o4.z = v2 > 0.f ? v2 : 0.f;
    o4.w = v3 > 0.f ? v3 : 0.f;
    ((float4*)A.out)[(size_t)node * 64 + lane] = o4;
}

// ---------------------------------------------------------------------------
extern "C" void kernel_launch(void* const* d_in, const int* in_sizes, int n_in,
                              void* d_out, int out_size, void* d_ws, size_t ws_size,
                              hipStream_t stream) {
    (void)out_size; (void)ws_size;
    const void* p_x = nullptr; const void* p_ei = nullptr; const void* p_W = nullptr;
    const void* p_small[3] = {nullptr, nullptr, nullptr}; int nsmall = 0;
    for (int i = 0; i < n_in; ++i) {
        switch (in_sizes[i]) {
            case N_NODES * IN_DIM:      p_x = d_in[i]; break;
            case 2 * N_EDGES:           p_ei = d_in[i]; break;
            case IN_DIM * OUT_DIM:      p_W = d_in[i]; break;
            case OUT_DIM:               if (nsmall < 3) p_small[nsmall++] = d_in[i]; break;
            default: break;
        }
    }
    if (!p_x)  p_x  = d_in[0];
    if (!p_ei) p_ei = d_in[1];
    if (!p_W)  p_W  = d_in[2];
    if (nsmall < 3) { p_small[0] = d_in[3]; p_small[1] = d_in[4]; p_small[2] = d_in[5]; }

    char* ws = (char*)d_ws;
    size_t off = 0;
    auto alloc = [&](size_t bytes) -> void* {
        void* p = ws + off;
        off = (off + bytes + 255) & ~(size_t)255;
        return p;
    };
    Args A;
    A.Wt      = (__bf16*)alloc((size_t)IN_DIM * OUT_DIM * 2);
    A.h       = (__bf16*)alloc((size_t)N_NODES * OUT_DIM * 2);
    A.a_src   = (float*)alloc((size_t)N_NODES * HEADS * 4);
    A.a_dst   = (float*)alloc((size_t)N_NODES * HEADS * 4);
    A.counts  = (int*)alloc((size_t)N_NODES * 4);
    A.loc     = (int*)alloc((size_t)N_NODES * 4);
    A.bsum    = (int*)alloc(NBLK * 4);
    A.bpref   = (int*)alloc(NBLK * 4);
    A.offsets = (int*)alloc((size_t)(N_NODES + 1) * 4);
    A.cursor  = (int*)alloc((size_t)N_NODES * 4);
    A.csr_src = (int*)alloc((size_t)TOT_EDGES * 4);

    A.x     = (const float*)p_x;
    A.ei    = (const int*)p_ei;
    A.W     = (const float*)p_W;
    A.att_s = (const float*)p_small[0];
    A.att_d = (const float*)p_small[1];
    A.bias  = (const float*)p_small[2];
    A.out   = (float*)d_out;

    hipMemsetAsync(A.counts, 0, (size_t)N_NODES * 4, stream);
    k_wt<<<dim3(IN_DIM), dim3(OUT_DIM), 0, stream>>>(A);
    k_gemm_hist<<<dim3(GBLK + HBLK), dim3(256), 0, stream>>>(A);
    k_scanA<<<dim3(NBLK), dim3(SBLK), 0, stream>>>(A);
    k_scanB<<<dim3(1), dim3(64), 0, stream>>>(A);
    k_scanC<<<dim3((N_NODES + 255) / 256), dim3(256), 0, stream>>>(A);
    k_fill<<<dim3((TOT_EDGES + 255) / 256), dim3(256), 0, stream>>>(A);
    k_agg<<<dim3((N_NODES + 3) / 4), dim3(256), 0, stream>>>(A);
}